// Round 2
// baseline (3391.341 us; speedup 1.0000x reference)
//
#include <hip/hip_runtime.h>
#include <hip/hip_bf16.h>

typedef __hip_bfloat16 bf16;

#define NB 8
#define SEQ 1024
#define HEADS 16
#define HD 64
#define EMB 1024

// -------- Kernel 1: per-head linear projection: out[n][h][l][e] = sum_d in[n][l][h*64+d] * W[e][d]
// in: (N, SEQ, EMB) f32. W: (64,64) f32 torch-Linear convention (x @ W.T). out: (N,H,SEQ,64) bf16
__global__ __launch_bounds__(256) void proj_kernel(
    const float* __restrict__ in, const float* __restrict__ W, bf16* __restrict__ out)
{
    __shared__ float Wt[64 * 64];   // Wt[d][e] = W[e][d] (transposed: stride-1 reads over e)
    __shared__ float xs[4][64];
    const int t = threadIdx.x;
    for (int i = t; i < 4096; i += 256)
        Wt[(i & 63) * 64 + (i >> 6)] = W[i];
    const long long vbase = (long long)blockIdx.x * 4;
    xs[t >> 6][t & 63] = in[vbase * 64 + t];
    __syncthreads();
    const int vl = t >> 6, e = t & 63;
    float acc = 0.f;
#pragma unroll
    for (int d = 0; d < 64; ++d)
        acc = fmaf(xs[vl][d], Wt[d * 64 + e], acc);
    const long long v = vbase + vl;           // v = (n*SEQ + l)*HEADS + h
    const int n = (int)(v >> 14);             // / (SEQ*HEADS)
    const int l = (int)((v >> 4) & 1023);
    const int h = (int)(v & 15);
    out[((((long long)n * HEADS + h) << 10) + l) * 64 + e] = __float2bfloat16(acc);
}

// -------- Kernel 2: flash attention per (n,h), 32-query tile, 32-key chunks
// qp/kp/vp: (N,H,SEQ,64) bf16. mask: (N,1,SEQ,SEQ) int32. attn_out: (N,SEQ,EMB) bf16
__global__ __launch_bounds__(256) void attn_kernel(
    const bf16* __restrict__ qp, const bf16* __restrict__ kp, const bf16* __restrict__ vp,
    const int* __restrict__ mask, bf16* __restrict__ attn_out)
{
    const int qt = blockIdx.x;
    const int nh = blockIdx.y;
    const int n = nh >> 4, h = nh & 15;
    const bf16* Q = qp + (size_t)nh * (SEQ * HD);
    const bf16* K = kp + (size_t)nh * (SEQ * HD);
    const bf16* V = vp + (size_t)nh * (SEQ * HD);
    __shared__ float Qs[32][65];
    __shared__ float Ks[32][65];
    __shared__ float Vs[32][65];
    __shared__ float Ps[32][33];
    __shared__ float m_s[32], l_s[32], alpha_s[32];
    const int t = threadIdx.x;
    const int q0 = qt * 32;
    // scale = 1/sqrt(EMBED) = 1/32, folded into Q. Mask fill = -1e20/32 (mask applied BEFORE scale).
    for (int i = t; i < 2048; i += 256) {
        int r = i >> 6, d = i & 63;
        Qs[r][d] = __bfloat162float(Q[(size_t)(q0 + r) * 64 + d]) * 0.03125f;
    }
    if (t < 32) { m_s[t] = -3.4e38f; l_s[t] = 0.f; }
    const int q  = t >> 3;
    const int k4 = (t & 7) * 4;
    const int d0 = (t & 7) * 8;
    float O[8] = {0.f, 0.f, 0.f, 0.f, 0.f, 0.f, 0.f, 0.f};
    for (int kc = 0; kc < 32; ++kc) {
        __syncthreads();   // previous Ps/Vs fully consumed
        for (int i = t; i < 2048; i += 256) {
            int r = i >> 6, d = i & 63;
            Ks[r][d] = __bfloat162float(K[(size_t)(kc * 32 + r) * 64 + d]);
            Vs[r][d] = __bfloat162float(V[(size_t)(kc * 32 + r) * 64 + d]);
        }
        __syncthreads();
        // phase A: scores — each thread 4 scores (same q row)
        float s0 = 0.f, s1 = 0.f, s2 = 0.f, s3 = 0.f;
#pragma unroll
        for (int d = 0; d < 64; ++d) {
            float qv = Qs[q][d];
            s0 = fmaf(qv, Ks[k4 + 0][d], s0);
            s1 = fmaf(qv, Ks[k4 + 1][d], s1);
            s2 = fmaf(qv, Ks[k4 + 2][d], s2);
            s3 = fmaf(qv, Ks[k4 + 3][d], s3);
        }
        const int* mrow = mask + ((size_t)n * SEQ + (q0 + q)) * SEQ + kc * 32 + k4;
        Ps[q][k4 + 0] = mrow[0] ? s0 : -3.125e18f;
        Ps[q][k4 + 1] = mrow[1] ? s1 : -3.125e18f;
        Ps[q][k4 + 2] = mrow[2] ? s2 : -3.125e18f;
        Ps[q][k4 + 3] = mrow[3] ? s3 : -3.125e18f;
        __syncthreads();
        // phase B: online softmax update (one thread per q row)
        if (t < 32) {
            float m_old = m_s[t];
            float mc = m_old;
            for (int j = 0; j < 32; ++j) mc = fmaxf(mc, Ps[t][j]);
            float alpha = __expf(m_old - mc);
            float sum = 0.f;
            for (int j = 0; j < 32; ++j) {
                float p = __expf(Ps[t][j] - mc);
                Ps[t][j] = p;
                sum += p;
            }
            m_s[t] = mc;
            l_s[t] = l_s[t] * alpha + sum;
            alpha_s[t] = alpha;
        }
        __syncthreads();
        // phase C: O = O*alpha + P @ V   (thread owns 8 d-elems of one q row)
        float a = alpha_s[q];
#pragma unroll
        for (int i = 0; i < 8; ++i) O[i] *= a;
        for (int k = 0; k < 32; ++k) {
            float p = Ps[q][k];
#pragma unroll
            for (int i = 0; i < 8; ++i)
                O[i] = fmaf(p, Vs[k][d0 + i], O[i]);
        }
    }
    __syncthreads();
    const float linv = 1.0f / l_s[q];
    bf16* orow = attn_out + ((size_t)n * SEQ + (q0 + q)) * EMB + h * 64 + d0;
#pragma unroll
    for (int i = 0; i < 8; ++i) orow[i] = __float2bfloat16(O[i] * linv);
}

// -------- Kernel 3: out = A(8192x1024) @ Wo.T + bo; A bf16, Wo/bo f32, out f32, f32 acc
__global__ __launch_bounds__(256) void out_gemm(
    const bf16* __restrict__ A, const float* __restrict__ Wo,
    const float* __restrict__ bo, float* __restrict__ out)
{
    __shared__ float As[64][33];
    __shared__ float Ws[32][65];   // Ws[c][e] = Wo[e0+e][kc*32+c]
    const int t = threadIdx.x;
    const int e0 = blockIdx.x * 64;
    const int r0 = blockIdx.y * 64;
    const int ty = t >> 4, tx = t & 15;
    float acc[4][4] = {};
    for (int kc = 0; kc < 32; ++kc) {
        __syncthreads();
        for (int i = t; i < 2048; i += 256) {
            int r = i >> 5, c = i & 31;
            As[r][c] = __bfloat162float(A[(size_t)(r0 + r) * EMB + kc * 32 + c]);
        }
        for (int i = t; i < 2048; i += 256) {
            int e = i >> 5, c = i & 31;
            Ws[c][e] = Wo[(size_t)(e0 + e) * EMB + kc * 32 + c];
        }
        __syncthreads();
        for (int c = 0; c < 32; ++c) {
            float a[4], w[4];
#pragma unroll
            for (int i = 0; i < 4; ++i) a[i] = As[ty * 4 + i][c];
#pragma unroll
            for (int j = 0; j < 4; ++j) w[j] = Ws[c][tx * 4 + j];
#pragma unroll
            for (int i = 0; i < 4; ++i)
#pragma unroll
                for (int j = 0; j < 4; ++j)
                    acc[i][j] = fmaf(a[i], w[j], acc[i][j]);
        }
    }
    float bv[4];
#pragma unroll
    for (int j = 0; j < 4; ++j) bv[j] = bo[e0 + tx * 4 + j];
#pragma unroll
    for (int i = 0; i < 4; ++i)
#pragma unroll
        for (int j = 0; j < 4; ++j)
            out[(size_t)(r0 + ty * 4 + i) * EMB + e0 + tx * 4 + j] = acc[i][j] + bv[j];
}

extern "C" void kernel_launch(void* const* d_in, const int* in_sizes, int n_in,
                              void* d_out, int out_size, void* d_ws, size_t ws_size,
                              hipStream_t stream) {
    const float* values = (const float*)d_in[0];
    const float* keys   = (const float*)d_in[1];
    const float* query  = (const float*)d_in[2];
    const int*   mask   = (const int*)d_in[3];
    const float* Wv     = (const float*)d_in[4];
    const float* Wk     = (const float*)d_in[5];
    const float* Wq     = (const float*)d_in[6];
    const float* Wo     = (const float*)d_in[7];
    const float* bo     = (const float*)d_in[8];
    float* out = (float*)d_out;

    const size_t per = (size_t)NB * HEADS * SEQ * HD;  // 8.4M elems
    bf16* qp   = (bf16*)d_ws;
    bf16* kp   = qp + per;
    bf16* vp   = kp + per;
    bf16* attn = vp + per;   // (N*SEQ, EMB) bf16

    const int nproj_blocks = NB * SEQ * HEADS / 4;  // 32768
    proj_kernel<<<nproj_blocks, 256, 0, stream>>>(query,  Wq, qp);
    proj_kernel<<<nproj_blocks, 256, 0, stream>>>(keys,   Wk, kp);
    proj_kernel<<<nproj_blocks, 256, 0, stream>>>(values, Wv, vp);

    attn_kernel<<<dim3(SEQ / 32, NB * HEADS), 256, 0, stream>>>(qp, kp, vp, mask, attn);

    out_gemm<<<dim3(EMB / 64, NB * SEQ / 64), 256, 0, stream>>>(attn, Wo, bo, out);
}

// Round 3
// 341.729 us; speedup vs baseline: 9.9241x; 9.9241x over previous
//
#include <hip/hip_runtime.h>
#include <hip/hip_bf16.h>

using bf16x8 = __attribute__((ext_vector_type(8))) __bf16;
using f32x4  = __attribute__((ext_vector_type(4))) float;

#define NB 8
#define SEQ 1024
#define HEADS 16
#define HD 64
#define EMB 1024
#define ATT_SCALE 0.03125f   /* 1/sqrt(EMBED) */
#define MASKVAL  -3.125e18f  /* -1e20 * ATT_SCALE (mask applied BEFORE scaling) */

// ---------------- Kernel 1: fused QKV projection, MFMA ----------------
// X: (N,SEQ,EMB) f32, rows of 64 per (n,l,h). W: (64,64) f32 (x @ W.T).
// out: (N,H,SEQ,64) bf16. blockIdx.y selects projection; block = 64 rows.
__global__ __launch_bounds__(256, 4) void proj_mfma(
    const float* __restrict__ q_in, const float* __restrict__ k_in, const float* __restrict__ v_in,
    const float* __restrict__ Wq, const float* __restrict__ Wk, const float* __restrict__ Wv,
    __bf16* __restrict__ qp, __bf16* __restrict__ kp, __bf16* __restrict__ vp)
{
    const int z = blockIdx.y;
    const float* X  = (z == 0) ? q_in : (z == 1) ? k_in : v_in;
    const float* Wf = (z == 0) ? Wq   : (z == 1) ? Wk   : Wv;
    __bf16* out     = (z == 0) ? qp   : (z == 1) ? kp   : vp;

    __shared__ __align__(16) __bf16 Wb[64 * 72];  // Wb[e][d], stride 72 (pad)
    __shared__ __align__(16) __bf16 Xb[64 * 72];  // Xb[row][d]
    const int t = threadIdx.x;
    for (int i = t; i < 4096; i += 256)
        Wb[(i >> 6) * 72 + (i & 63)] = (__bf16)Wf[i];
    const int r0 = blockIdx.x * 64;
    {
        const int row = t >> 2, seg = (t & 3) * 16;
        union { __bf16 b[16]; uint4 u[2]; } tmp;
        #pragma unroll
        for (int jj = 0; jj < 4; ++jj) {
            float4 f = *(const float4*)&X[(size_t)(r0 + row) * 64 + seg + jj * 4];
            tmp.b[jj*4+0] = (__bf16)f.x; tmp.b[jj*4+1] = (__bf16)f.y;
            tmp.b[jj*4+2] = (__bf16)f.z; tmp.b[jj*4+3] = (__bf16)f.w;
        }
        *(uint4*)&Xb[row * 72 + seg]     = tmp.u[0];
        *(uint4*)&Xb[row * 72 + seg + 8] = tmp.u[1];
    }
    __syncthreads();
    const int w = t >> 6, lane = t & 63, quad = lane >> 4, lr = lane & 15;
    bf16x8 af[2];
    #pragma unroll
    for (int ks = 0; ks < 2; ++ks)
        af[ks] = *(const bf16x8*)&Xb[(w * 16 + lr) * 72 + ks * 32 + quad * 8];
    const f32x4 zero4 = {0.f, 0.f, 0.f, 0.f};
    f32x4 acc[4];
    #pragma unroll
    for (int et = 0; et < 4; ++et) {
        acc[et] = zero4;
        #pragma unroll
        for (int ks = 0; ks < 2; ++ks) {
            bf16x8 bfrag = *(const bf16x8*)&Wb[(et * 16 + lr) * 72 + ks * 32 + quad * 8];
            acc[et] = __builtin_amdgcn_mfma_f32_16x16x32_bf16(af[ks], bfrag, acc[et], 0, 0, 0);
        }
    }
    #pragma unroll
    for (int et = 0; et < 4; ++et)
        #pragma unroll
        for (int rr = 0; rr < 4; ++rr) {
            int g = r0 + w * 16 + quad * 4 + rr;          // g = (n*1024+l)*16+h
            int n = g >> 14, l = (g >> 4) & 1023, hh = g & 15;
            out[(size_t)(n * 16 + hh) * 65536 + l * 64 + et * 16 + lr] = (__bf16)acc[et][rr];
        }
}

// ---------------- Kernel 2: MFMA flash attention ----------------
// qp/kp/vp: (N,H,SEQ,64) bf16. mask: (N,1,SEQ,SEQ) i32. attn_out: (N,SEQ,EMB) bf16.
// Block: 256 thr = 4 waves; 64 queries per block (16/wave); K/V chunks of 64.
__global__ __launch_bounds__(256, 4) void attn_mfma(
    const __bf16* __restrict__ qp, const __bf16* __restrict__ kp, const __bf16* __restrict__ vp,
    const int* __restrict__ mask, __bf16* __restrict__ attn_out)
{
    __shared__ __align__(16) __bf16 Qs[64 * 72];      // [q][d]
    __shared__ __align__(16) __bf16 Ks[64 * 72];      // [key][d]
    __shared__ __align__(16) __bf16 Vt[64 * 72];      // [d][key]  (transposed)
    __shared__ __align__(16) __bf16 Ps[4][16 * 72];   // per-wave [q][key]
    const int t = threadIdx.x;
    const int w = t >> 6, lane = t & 63, quad = lane >> 4, lr = lane & 15;
    const int qt = blockIdx.x, nh = blockIdx.y;
    const int n = nh >> 4, h = nh & 15;
    const int q0 = qt * 64;
    const __bf16* Q = qp + (size_t)nh * (SEQ * HD);
    const __bf16* K = kp + (size_t)nh * (SEQ * HD);
    const __bf16* V = vp + (size_t)nh * (SEQ * HD);
    const int* mbase = mask + (size_t)n * (SEQ * SEQ);

    // stage Q tile (64 x 64)
    for (int c = t; c < 512; c += 256) {
        int row = c >> 3, c8 = c & 7;
        *(uint4*)&Qs[row * 72 + c8 * 8] = *(const uint4*)&Q[(size_t)(q0 + row) * 64 + c8 * 8];
    }
    __syncthreads();
    bf16x8 qfrag[2];
    #pragma unroll
    for (int ks = 0; ks < 2; ++ks)
        qfrag[ks] = *(const bf16x8*)&Qs[(w * 16 + lr) * 72 + ks * 32 + quad * 8];

    const f32x4 zero4 = {0.f, 0.f, 0.f, 0.f};
    f32x4 O[4];  // 4 d-tiles; rows = quad*4+r
    #pragma unroll
    for (int dt = 0; dt < 4; ++dt) O[dt] = zero4;
    float m_run[4], l_run[4];
    #pragma unroll
    for (int r = 0; r < 4; ++r) { m_run[r] = -3.0e38f; l_run[r] = 0.f; }

    for (int kc = 0; kc < 16; ++kc) {
        __syncthreads();   // all waves done with previous Ks/Vt
        for (int c = t; c < 512; c += 256) {
            int row = c >> 3, c8 = c & 7;
            *(uint4*)&Ks[row * 72 + c8 * 8] =
                *(const uint4*)&K[(size_t)(kc * 64 + row) * 64 + c8 * 8];
            int key = c & 63, dc = c >> 6;
            union { __bf16 b[8]; uint4 u; } vv;
            vv.u = *(const uint4*)&V[(size_t)(kc * 64 + key) * 64 + dc * 8];
            #pragma unroll
            for (int j = 0; j < 8; ++j) Vt[(dc * 8 + j) * 72 + key] = vv.b[j];
        }
        __syncthreads();
        // QK^T: S tiles 16q x 64k per wave
        f32x4 S[4];
        #pragma unroll
        for (int kt = 0; kt < 4; ++kt) {
            S[kt] = zero4;
            #pragma unroll
            for (int ks = 0; ks < 2; ++ks) {
                bf16x8 kf = *(const bf16x8*)&Ks[(kt * 16 + lr) * 72 + ks * 32 + quad * 8];
                S[kt] = __builtin_amdgcn_mfma_f32_16x16x32_bf16(qfrag[ks], kf, S[kt], 0, 0, 0);
            }
        }
        // mask + scale + online softmax; row = q0 + w*16 + quad*4 + r, col = kc*64 + kt*16 + lr
        float p0[4], p1[4], p2[4], p3[4];
        #pragma unroll
        for (int r = 0; r < 4; ++r) {
            const int* mrow = mbase + (size_t)(q0 + w * 16 + quad * 4 + r) * SEQ + kc * 64 + lr;
            float s0 = mrow[0]  ? S[0][r] * ATT_SCALE : MASKVAL;
            float s1 = mrow[16] ? S[1][r] * ATT_SCALE : MASKVAL;
            float s2 = mrow[32] ? S[2][r] * ATT_SCALE : MASKVAL;
            float s3 = mrow[48] ? S[3][r] * ATT_SCALE : MASKVAL;
            float mx = fmaxf(fmaxf(s0, s1), fmaxf(s2, s3));
            #pragma unroll
            for (int i = 1; i < 16; i <<= 1) mx = fmaxf(mx, __shfl_xor(mx, i, 64));
            float mnew = fmaxf(m_run[r], mx);
            float e0 = __expf(s0 - mnew), e1 = __expf(s1 - mnew);
            float e2 = __expf(s2 - mnew), e3 = __expf(s3 - mnew);
            float sum = e0 + e1 + e2 + e3;
            #pragma unroll
            for (int i = 1; i < 16; i <<= 1) sum += __shfl_xor(sum, i, 64);
            float alpha = __expf(m_run[r] - mnew);
            m_run[r] = mnew;
            l_run[r] = l_run[r] * alpha + sum;
            #pragma unroll
            for (int dt = 0; dt < 4; ++dt) O[dt][r] *= alpha;
            p0[r] = e0; p1[r] = e1; p2[r] = e2; p3[r] = e3;
        }
        // P -> LDS (bf16), per-wave region: row=quad*4+r, col=kt*16+lr
        #pragma unroll
        for (int r = 0; r < 4; ++r) {
            Ps[w][(quad * 4 + r) * 72 +  0 + lr] = (__bf16)p0[r];
            Ps[w][(quad * 4 + r) * 72 + 16 + lr] = (__bf16)p1[r];
            Ps[w][(quad * 4 + r) * 72 + 32 + lr] = (__bf16)p2[r];
            Ps[w][(quad * 4 + r) * 72 + 48 + lr] = (__bf16)p3[r];
        }
        __syncthreads();   // P visibility (conservative) before PV reads
        // PV: O += P @ V
        #pragma unroll
        for (int ks = 0; ks < 2; ++ks) {
            bf16x8 pf = *(const bf16x8*)&Ps[w][lr * 72 + ks * 32 + quad * 8];
            #pragma unroll
            for (int dt = 0; dt < 4; ++dt) {
                bf16x8 vf = *(const bf16x8*)&Vt[(dt * 16 + lr) * 72 + ks * 32 + quad * 8];
                O[dt] = __builtin_amdgcn_mfma_f32_16x16x32_bf16(pf, vf, O[dt], 0, 0, 0);
            }
        }
    }
    float linv[4];
    #pragma unroll
    for (int r = 0; r < 4; ++r) linv[r] = 1.0f / l_run[r];
    #pragma unroll
    for (int dt = 0; dt < 4; ++dt)
        #pragma unroll
        for (int r = 0; r < 4; ++r) {
            int q = q0 + w * 16 + quad * 4 + r;
            attn_out[((size_t)n * SEQ + q) * EMB + h * 64 + dt * 16 + lr] =
                (__bf16)(O[dt][r] * linv[r]);
        }
}

// ---------------- Kernel 3a: Wo f32 -> bf16 ----------------
__global__ __launch_bounds__(256) void cvt_wo(const float* __restrict__ Wo, __bf16* __restrict__ Wob)
{
    int i = blockIdx.x * 256 + threadIdx.x;   // 4 elems each
    float4 f = *(const float4*)&Wo[(size_t)i * 4];
    union { __bf16 b[4]; uint2 u; } tmp;
    tmp.b[0] = (__bf16)f.x; tmp.b[1] = (__bf16)f.y; tmp.b[2] = (__bf16)f.z; tmp.b[3] = (__bf16)f.w;
    *(uint2*)&Wob[(size_t)i * 4] = tmp.u;
}

// ---------------- Kernel 3b: out = A(8192x1024) @ Wob^T + bo, MFMA ----------------
// 128x128 tile, 4 waves (2x2), each wave 64x64 = 16 MFMA tiles.
__global__ __launch_bounds__(256, 2) void out_gemm_mfma(
    const __bf16* __restrict__ A, const __bf16* __restrict__ B,
    const float* __restrict__ bo, float* __restrict__ out)
{
    __shared__ __align__(16) __bf16 As[128 * 40];  // [row][k], pad 40
    __shared__ __align__(16) __bf16 Bs[128 * 40];  // [e][k]
    const int t = threadIdx.x, w = t >> 6, lane = t & 63, quad = lane >> 4, lr = lane & 15;
    const int wr = (w >> 1) * 64, wc = (w & 1) * 64;
    const int r0 = blockIdx.y * 128, e0 = blockIdx.x * 128;
    const f32x4 zero4 = {0.f, 0.f, 0.f, 0.f};
    f32x4 acc[4][4];
    #pragma unroll
    for (int mt = 0; mt < 4; ++mt)
        #pragma unroll
        for (int nt = 0; nt < 4; ++nt) acc[mt][nt] = zero4;
    for (int k0 = 0; k0 < 1024; k0 += 32) {
        __syncthreads();
        for (int c = t; c < 512; c += 256) {
            int row = c >> 2, c8 = c & 3;
            *(uint4*)&As[row * 40 + c8 * 8] =
                *(const uint4*)&A[(size_t)(r0 + row) * EMB + k0 + c8 * 8];
            *(uint4*)&Bs[row * 40 + c8 * 8] =
                *(const uint4*)&B[(size_t)(e0 + row) * EMB + k0 + c8 * 8];
        }
        __syncthreads();
        bf16x8 af[4], bf[4];
        #pragma unroll
        for (int mt = 0; mt < 4; ++mt)
            af[mt] = *(const bf16x8*)&As[(wr + mt * 16 + lr) * 40 + quad * 8];
        #pragma unroll
        for (int nt = 0; nt < 4; ++nt)
            bf[nt] = *(const bf16x8*)&Bs[(wc + nt * 16 + lr) * 40 + quad * 8];
        #pragma unroll
        for (int mt = 0; mt < 4; ++mt)
            #pragma unroll
            for (int nt = 0; nt < 4; ++nt)
                acc[mt][nt] = __builtin_amdgcn_mfma_f32_16x16x32_bf16(af[mt], bf[nt], acc[mt][nt], 0, 0, 0);
    }
    float bv[4];
    #pragma unroll
    for (int nt = 0; nt < 4; ++nt) bv[nt] = bo[e0 + wc + nt * 16 + lr];
    #pragma unroll
    for (int mt = 0; mt < 4; ++mt)
        #pragma unroll
        for (int nt = 0; nt < 4; ++nt)
            #pragma unroll
            for (int rr = 0; rr < 4; ++rr)
                out[(size_t)(r0 + wr + mt * 16 + quad * 4 + rr) * EMB + e0 + wc + nt * 16 + lr] =
                    acc[mt][nt][rr] + bv[nt];
}

extern "C" void kernel_launch(void* const* d_in, const int* in_sizes, int n_in,
                              void* d_out, int out_size, void* d_ws, size_t ws_size,
                              hipStream_t stream) {
    const float* values = (const float*)d_in[0];
    const float* keys   = (const float*)d_in[1];
    const float* query  = (const float*)d_in[2];
    const int*   mask   = (const int*)d_in[3];
    const float* Wv     = (const float*)d_in[4];
    const float* Wk     = (const float*)d_in[5];
    const float* Wq     = (const float*)d_in[6];
    const float* Wo     = (const float*)d_in[7];
    const float* bo     = (const float*)d_in[8];
    float* out = (float*)d_out;

    const size_t per = (size_t)NB * HEADS * SEQ * HD;  // 8.4M elems
    __bf16* qp   = (__bf16*)d_ws;
    __bf16* kp   = qp + per;
    __bf16* vp   = kp + per;
    __bf16* attn = vp + per;                 // (N*SEQ, EMB) bf16
    __bf16* Wob  = attn + (size_t)NB * SEQ * EMB;

    proj_mfma<<<dim3(2048, 3), 256, 0, stream>>>(query, keys, values, Wq, Wk, Wv, qp, kp, vp);
    cvt_wo<<<1024, 256, 0, stream>>>(Wo, Wob);
    attn_mfma<<<dim3(SEQ / 64, NB * HEADS), 256, 0, stream>>>(qp, kp, vp, mask, attn);
    out_gemm_mfma<<<dim3(EMB / 128, NB * SEQ / 128), 256, 0, stream>>>(attn, Wob, bo, out);
}

// Round 4
// 306.026 us; speedup vs baseline: 11.0819x; 1.1167x over previous
//
#include <hip/hip_runtime.h>
#include <hip/hip_bf16.h>

using bf16x8 = __attribute__((ext_vector_type(8))) __bf16;
using f32x4  = __attribute__((ext_vector_type(4))) float;

#define NB 8
#define SEQ 1024
#define HEADS 16
#define HD 64
#define EMB 1024
#define MASKVAL  -3.125e18f  /* -1e20 * (1/32); mask applied BEFORE the /sqrt(EMBED) scale */

// ---------------- Kernel 0: bit-pack mask (N,SEQ,SEQ) i32 -> (N,SEQ,SEQ/64) u64 ----------------
__global__ __launch_bounds__(256) void mask_pack(const int* __restrict__ mask,
                                                 unsigned long long* __restrict__ mp)
{
    const int row = blockIdx.x, n = blockIdx.y, t = threadIdx.x;
    const int w = t >> 6, lane = t & 63;
    const int* m = mask + ((size_t)n * SEQ + row) * SEQ;
    #pragma unroll
    for (int i = 0; i < 4; ++i) {
        unsigned long long b = __ballot(m[i * 256 + w * 64 + lane] != 0);
        if (lane == 0) mp[((size_t)n * SEQ + row) * 16 + i * 4 + w] = b;
    }
}

// ---------------- Kernel 1: per-head projection, MFMA, l-tiled blocks ----------------
// X: (N,SEQ,EMB) f32. W: (64,64) f32 (x @ W.T).
// z=0: Q out (N,H,SEQ,64), pre-scaled by 1/32.  z=1: K out (N,H,SEQ,64).
// z=2: V out TRANSPOSED (N,H,64,SEQ) via LDS epilogue.
__global__ __launch_bounds__(256, 4) void proj_mfma(
    const float* __restrict__ q_in, const float* __restrict__ k_in, const float* __restrict__ v_in,
    const float* __restrict__ Wq, const float* __restrict__ Wk, const float* __restrict__ Wv,
    __bf16* __restrict__ qp, __bf16* __restrict__ kp, __bf16* __restrict__ vpt)
{
    const int z = blockIdx.z;
    const float* X  = (z == 0) ? q_in : (z == 1) ? k_in : v_in;
    const float* Wf = (z == 0) ? Wq   : (z == 1) ? Wk   : Wv;

    __shared__ __align__(16) __bf16 Wb[64 * 72];  // Wb[e][d]
    __shared__ __align__(16) __bf16 Xb[64 * 72];  // Xb[l_local][d]; reused as Tb[e][l_local] for z==2
    const int t = threadIdx.x;
    const int nh = blockIdx.y, n = nh >> 4, h = nh & 15;
    const int l0 = blockIdx.x * 64;
    for (int i = t; i < 4096; i += 256)
        Wb[(i >> 6) * 72 + (i & 63)] = (__bf16)Wf[i];
    {
        const int row = t >> 2, seg = (t & 3) * 16;
        const float* src = X + ((size_t)(n * SEQ + l0 + row)) * EMB + h * 64 + seg;
        union { __bf16 b[16]; uint4 u[2]; } tmp;
        #pragma unroll
        for (int jj = 0; jj < 4; ++jj) {
            float4 f = ((const float4*)src)[jj];
            tmp.b[jj*4+0] = (__bf16)f.x; tmp.b[jj*4+1] = (__bf16)f.y;
            tmp.b[jj*4+2] = (__bf16)f.z; tmp.b[jj*4+3] = (__bf16)f.w;
        }
        *(uint4*)&Xb[row * 72 + seg]     = tmp.u[0];
        *(uint4*)&Xb[row * 72 + seg + 8] = tmp.u[1];
    }
    __syncthreads();
    const int w = t >> 6, lane = t & 63, quad = lane >> 4, lr = lane & 15;
    bf16x8 af[2];
    #pragma unroll
    for (int ks = 0; ks < 2; ++ks)
        af[ks] = *(const bf16x8*)&Xb[(w * 16 + lr) * 72 + ks * 32 + quad * 8];
    const f32x4 zero4 = {0.f, 0.f, 0.f, 0.f};
    f32x4 acc[4];
    #pragma unroll
    for (int et = 0; et < 4; ++et) {
        acc[et] = zero4;
        #pragma unroll
        for (int ks = 0; ks < 2; ++ks) {
            bf16x8 bfrag = *(const bf16x8*)&Wb[(et * 16 + lr) * 72 + ks * 32 + quad * 8];
            acc[et] = __builtin_amdgcn_mfma_f32_16x16x32_bf16(af[ks], bfrag, acc[et], 0, 0, 0);
        }
    }
    if (z == 0) {
        #pragma unroll
        for (int et = 0; et < 4; ++et) acc[et] *= 0.03125f;   // fold 1/sqrt(EMBED) into Q (exact pow2)
    }
    if (z < 2) {
        __bf16* out = (z == 0) ? qp : kp;
        #pragma unroll
        for (int et = 0; et < 4; ++et)
            #pragma unroll
            for (int rr = 0; rr < 4; ++rr)
                out[(size_t)nh * 65536 + (size_t)(l0 + w * 16 + quad * 4 + rr) * 64 + et * 16 + lr] =
                    (__bf16)acc[et][rr];
    } else {
        __syncthreads();   // all waves done reading Xb (fragments live in regs)
        #pragma unroll
        for (int et = 0; et < 4; ++et)
            #pragma unroll
            for (int rr = 0; rr < 4; ++rr)
                Xb[(et * 16 + lr) * 72 + w * 16 + quad * 4 + rr] = (__bf16)acc[et][rr];  // Tb[e][l]
        __syncthreads();
        const int e = t >> 2, seg = (t & 3) * 16;
        uint4 a = *(uint4*)&Xb[e * 72 + seg];
        uint4 b = *(uint4*)&Xb[e * 72 + seg + 8];
        __bf16* dst = vpt + (size_t)nh * 65536 + (size_t)e * SEQ + l0 + seg;
        *(uint4*)&dst[0] = a;
        *(uint4*)&dst[8] = b;
    }
}

// ---------------- Kernel 2: MFMA flash attention, transposed-S scheme ----------------
// qp/kp: (N,H,SEQ,64) bf16 (Q pre-scaled). vpt: (N,H,64,SEQ) bf16. mp: packed mask.
// attn_out: (N,SEQ,EMB) bf16. 1D grid: nh = bid&127 (XCD-pins a head's q-tiles), qt = bid>>7.
__global__ __launch_bounds__(256, 4) void attn_mfma(
    const __bf16* __restrict__ qp, const __bf16* __restrict__ kp, const __bf16* __restrict__ vpt,
    const unsigned long long* __restrict__ mp, __bf16* __restrict__ attn_out)
{
    __shared__ __align__(16) __bf16 Ks[64 * 72];      // [key][d]
    __shared__ __align__(16) __bf16 Vt[64 * 72];      // [d][key]
    __shared__ __align__(16) __bf16 Ps[4][16 * 72];   // per-wave [q_local][key]
    const int t = threadIdx.x, w = t >> 6, lane = t & 63, quad = lane >> 4, lr = lane & 15;
    const int bid = blockIdx.x;
    const int nh = bid & 127, qt = bid >> 7;
    const int n = nh >> 4, h = nh & 15;
    const int q0 = qt * 64;
    const __bf16* Q  = qp  + (size_t)nh * 65536;
    const __bf16* K  = kp  + (size_t)nh * 65536;
    const __bf16* VT = vpt + (size_t)nh * 65536;
    const int qrow = q0 + w * 16 + lr;   // this lane's query (column index of S^T)
    bf16x8 qf[2];
    qf[0] = *(const bf16x8*)&Q[(size_t)qrow * 64 + quad * 8];
    qf[1] = *(const bf16x8*)&Q[(size_t)qrow * 64 + 32 + quad * 8];
    const unsigned long long* mrow = mp + ((size_t)n * SEQ + qrow) * 16;

    const f32x4 zero4 = {0.f, 0.f, 0.f, 0.f};
    f32x4 O[4];   // O^T tile: col=q (lane), row d = mt*16 + quad*4 + r
    #pragma unroll
    for (int mt = 0; mt < 4; ++mt) O[mt] = zero4;
    float m_run = -3.0e38f, l_run = 0.f;

    for (int kc = 0; kc < 16; ++kc) {
        __syncthreads();   // all waves done with previous Ks/Vt
        for (int c = t; c < 512; c += 256) {
            int row = c >> 3, c8 = c & 7;
            *(uint4*)&Ks[row * 72 + c8 * 8] =
                *(const uint4*)&K[(size_t)(kc * 64 + row) * 64 + c8 * 8];
            *(uint4*)&Vt[row * 72 + c8 * 8] =
                *(const uint4*)&VT[(size_t)row * SEQ + kc * 64 + c8 * 8];
        }
        const unsigned long long mword = mrow[kc];
        __syncthreads();
        // S^T = K @ Q^T : col = q, row = key = kt*16 + quad*4 + r
        f32x4 S[4];
        #pragma unroll
        for (int kt = 0; kt < 4; ++kt) {
            S[kt] = zero4;
            #pragma unroll
            for (int ks = 0; ks < 2; ++ks) {
                bf16x8 kf = *(const bf16x8*)&Ks[(kt * 16 + lr) * 72 + ks * 32 + quad * 8];
                S[kt] = __builtin_amdgcn_mfma_f32_16x16x32_bf16(kf, qf[ks], S[kt], 0, 0, 0);
            }
        }
        // mask (bit key_local = kt*16 + quad*4 + r) + online softmax, per-lane scalar state
        const unsigned int mlo = (unsigned int)(mword >> (quad * 4));
        const unsigned int mhi = (unsigned int)(mword >> (32 + quad * 4));
        float sv[16];
        #pragma unroll
        for (int kt = 0; kt < 4; ++kt)
            #pragma unroll
            for (int r = 0; r < 4; ++r) {
                unsigned int bits = (kt < 2) ? mlo : mhi;
                int sh = (kt & 1) * 16 + r;
                sv[kt * 4 + r] = ((bits >> sh) & 1u) ? S[kt][r] : MASKVAL;
            }
        float mx = sv[0];
        #pragma unroll
        for (int i = 1; i < 16; ++i) mx = fmaxf(mx, sv[i]);
        mx = fmaxf(mx, __shfl_xor(mx, 16, 64));
        mx = fmaxf(mx, __shfl_xor(mx, 32, 64));
        const float mnew = fmaxf(m_run, mx);
        float e[16], sum = 0.f;
        #pragma unroll
        for (int i = 0; i < 16; ++i) { e[i] = __expf(sv[i] - mnew); sum += e[i]; }
        sum += __shfl_xor(sum, 16, 64);
        sum += __shfl_xor(sum, 32, 64);
        const float alpha = __expf(m_run - mnew);
        m_run = mnew;
        l_run = l_run * alpha + sum;
        #pragma unroll
        for (int mt = 0; mt < 4; ++mt) O[mt] *= alpha;
        // P -> per-wave LDS: row q_local = lr, 4 consecutive keys per b64 write
        #pragma unroll
        for (int kt = 0; kt < 4; ++kt) {
            union { __bf16 b[4]; uint2 u; } pk;
            #pragma unroll
            for (int r = 0; r < 4; ++r) pk.b[r] = (__bf16)e[kt * 4 + r];
            *(uint2*)&Ps[w][lr * 72 + kt * 16 + quad * 4] = pk.u;
        }
        __asm__ __volatile__("s_waitcnt lgkmcnt(0)" ::: "memory");  // wave-local P visibility
        // O^T += V^T @ P^T : A = Vt rows d, B = P rows q
        #pragma unroll
        for (int ks = 0; ks < 2; ++ks) {
            bf16x8 pf = *(const bf16x8*)&Ps[w][lr * 72 + ks * 32 + quad * 8];
            #pragma unroll
            for (int mt = 0; mt < 4; ++mt) {
                bf16x8 vf = *(const bf16x8*)&Vt[(mt * 16 + lr) * 72 + ks * 32 + quad * 8];
                O[mt] = __builtin_amdgcn_mfma_f32_16x16x32_bf16(vf, pf, O[mt], 0, 0, 0);
            }
        }
    }
    const float linv = 1.0f / l_run;
    #pragma unroll
    for (int mt = 0; mt < 4; ++mt) {
        union { __bf16 b[4]; uint2 u; } pk;
        #pragma unroll
        for (int r = 0; r < 4; ++r) pk.b[r] = (__bf16)(O[mt][r] * linv);
        *(uint2*)&attn_out[((size_t)n * SEQ + qrow) * EMB + h * 64 + mt * 16 + quad * 4] = pk.u;
    }
}

// ---------------- Kernel 3a: Wo f32 -> bf16 ----------------
__global__ __launch_bounds__(256) void cvt_wo(const float* __restrict__ Wo, __bf16* __restrict__ Wob)
{
    int i = blockIdx.x * 256 + threadIdx.x;
    float4 f = *(const float4*)&Wo[(size_t)i * 4];
    union { __bf16 b[4]; uint2 u; } tmp;
    tmp.b[0] = (__bf16)f.x; tmp.b[1] = (__bf16)f.y; tmp.b[2] = (__bf16)f.z; tmp.b[3] = (__bf16)f.w;
    *(uint2*)&Wob[(size_t)i * 4] = tmp.u;
}

// ---------------- Kernel 3b: out = A(8192x1024) @ Wob^T + bo, MFMA ----------------
__global__ __launch_bounds__(256, 2) void out_gemm_mfma(
    const __bf16* __restrict__ A, const __bf16* __restrict__ B,
    const float* __restrict__ bo, float* __restrict__ out)
{
    __shared__ __align__(16) __bf16 As[128 * 40];
    __shared__ __align__(16) __bf16 Bs[128 * 40];
    const int t = threadIdx.x, w = t >> 6, lane = t & 63, quad = lane >> 4, lr = lane & 15;
    const int wr = (w >> 1) * 64, wc = (w & 1) * 64;
    const int r0 = blockIdx.y * 128, e0 = blockIdx.x * 128;
    const f32x4 zero4 = {0.f, 0.f, 0.f, 0.f};
    f32x4 acc[4][4];
    #pragma unroll
    for (int mt = 0; mt < 4; ++mt)
        #pragma unroll
        for (int nt = 0; nt < 4; ++nt) acc[mt][nt] = zero4;
    for (int k0 = 0; k0 < 1024; k0 += 32) {
        __syncthreads();
        for (int c = t; c < 512; c += 256) {
            int row = c >> 2, c8 = c & 3;
            *(uint4*)&As[row * 40 + c8 * 8] =
                *(const uint4*)&A[(size_t)(r0 + row) * EMB + k0 + c8 * 8];
            *(uint4*)&Bs[row * 40 + c8 * 8] =
                *(const uint4*)&B[(size_t)(e0 + row) * EMB + k0 + c8 * 8];
        }
        __syncthreads();
        bf16x8 af[4], bf[4];
        #pragma unroll
        for (int mt = 0; mt < 4; ++mt)
            af[mt] = *(const bf16x8*)&As[(wr + mt * 16 + lr) * 40 + quad * 8];
        #pragma unroll
        for (int nt = 0; nt < 4; ++nt)
            bf[nt] = *(const bf16x8*)&Bs[(wc + nt * 16 + lr) * 40 + quad * 8];
        #pragma unroll
        for (int mt = 0; mt < 4; ++mt)
            #pragma unroll
            for (int nt = 0; nt < 4; ++nt)
                acc[mt][nt] = __builtin_amdgcn_mfma_f32_16x16x32_bf16(af[mt], bf[nt], acc[mt][nt], 0, 0, 0);
    }
    float bv[4];
    #pragma unroll
    for (int nt = 0; nt < 4; ++nt) bv[nt] = bo[e0 + wc + nt * 16 + lr];
    #pragma unroll
    for (int mt = 0; mt < 4; ++mt)
        #pragma unroll
        for (int nt = 0; nt < 4; ++nt)
            #pragma unroll
            for (int rr = 0; rr < 4; ++rr)
                out[(size_t)(r0 + wr + mt * 16 + quad * 4 + rr) * EMB + e0 + wc + nt * 16 + lr] =
                    acc[mt][nt][rr] + bv[nt];
}

extern "C" void kernel_launch(void* const* d_in, const int* in_sizes, int n_in,
                              void* d_out, int out_size, void* d_ws, size_t ws_size,
                              hipStream_t stream) {
    const float* values = (const float*)d_in[0];
    const float* keys   = (const float*)d_in[1];
    const float* query  = (const float*)d_in[2];
    const int*   mask   = (const int*)d_in[3];
    const float* Wv     = (const float*)d_in[4];
    const float* Wk     = (const float*)d_in[5];
    const float* Wq     = (const float*)d_in[6];
    const float* Wo     = (const float*)d_in[7];
    const float* bo     = (const float*)d_in[8];
    float* out = (float*)d_out;

    const size_t per = (size_t)NB * HEADS * SEQ * HD;  // 8,388,608 elems
    __bf16* qp   = (__bf16*)d_ws;
    __bf16* kp   = qp + per;
    __bf16* vpt  = kp + per;                         // V transposed (N,H,64,SEQ)
    __bf16* attn = vpt + per;                        // (N*SEQ, EMB)
    __bf16* Wob  = attn + (size_t)NB * SEQ * EMB;
    unsigned long long* maskp = (unsigned long long*)(Wob + (size_t)EMB * EMB);

    mask_pack<<<dim3(SEQ, NB), 256, 0, stream>>>(mask, maskp);
    proj_mfma<<<dim3(16, 128, 3), 256, 0, stream>>>(query, keys, values, Wq, Wk, Wv, qp, kp, vpt);
    cvt_wo<<<1024, 256, 0, stream>>>(Wo, Wob);
    attn_mfma<<<2048, 256, 0, stream>>>(qp, kp, vpt, maskp, attn);
    out_gemm_mfma<<<dim3(EMB / 128, NB * SEQ / 128), 256, 0, stream>>>(attn, Wob, bo, out);
}

// Round 5
// 284.733 us; speedup vs baseline: 11.9106x; 1.0748x over previous
//
#include <hip/hip_runtime.h>
#include <hip/hip_bf16.h>

using bf16x8 = __attribute__((ext_vector_type(8))) __bf16;
using f32x4  = __attribute__((ext_vector_type(4))) float;

#define NB 8
#define SEQ 1024
#define HEADS 16
#define HD 64
#define EMB 1024

// exp domain: prefer native exp2 (one v_exp_f32), fold log2(e) into the Q prescale.
#if __has_builtin(__builtin_amdgcn_exp2f)
  #define EXPD(x) __builtin_amdgcn_exp2f(x)
  #define QSCALE  0.04508422f    /* (1/32) * log2(e) */
  #define MASKV  -4.5084e18f     /* -1e20 * QSCALE   */
#else
  #define EXPD(x) __expf(x)
  #define QSCALE  0.03125f
  #define MASKV  -3.125e18f
#endif

// ---------------- Kernel 0: bit-pack mask (N,SEQ,SEQ) i32 -> (N,SEQ,SEQ/64) u64 ----------------
__global__ __launch_bounds__(256) void mask_pack(const int* __restrict__ mask,
                                                 unsigned long long* __restrict__ mp)
{
    const int row = blockIdx.x, n = blockIdx.y, t = threadIdx.x;
    const int w = t >> 6, lane = t & 63;
    const int* m = mask + ((size_t)n * SEQ + row) * SEQ;
    #pragma unroll
    for (int i = 0; i < 4; ++i) {
        unsigned long long b = __ballot(m[i * 256 + w * 64 + lane] != 0);
        if (lane == 0) mp[((size_t)n * SEQ + row) * 16 + i * 4 + w] = b;
    }
}

// ---------------- Kernel 1: per-head projection, MFMA ----------------
// z=0: Q out (N,H,SEQ,64), pre-scaled by QSCALE.  z=1: K out.  z=2: V out transposed (N,H,64,SEQ).
__global__ __launch_bounds__(256, 4) void proj_mfma(
    const float* __restrict__ q_in, const float* __restrict__ k_in, const float* __restrict__ v_in,
    const float* __restrict__ Wq, const float* __restrict__ Wk, const float* __restrict__ Wv,
    __bf16* __restrict__ qp, __bf16* __restrict__ kp, __bf16* __restrict__ vpt)
{
    const int z = blockIdx.z;
    const float* X  = (z == 0) ? q_in : (z == 1) ? k_in : v_in;
    const float* Wf = (z == 0) ? Wq   : (z == 1) ? Wk   : Wv;

    __shared__ __align__(16) __bf16 Wb[64 * 72];  // Wb[e][d]
    __shared__ __align__(16) __bf16 Xb[64 * 72];  // Xb[l][d]; reused as output tile
    const int t = threadIdx.x;
    const int nh = blockIdx.y, n = nh >> 4, h = nh & 15;
    const int l0 = blockIdx.x * 64;
    for (int i = t; i < 4096; i += 256)
        Wb[(i >> 6) * 72 + (i & 63)] = (__bf16)Wf[i];
    {
        const int row = t >> 2, seg = (t & 3) * 16;
        const float* src = X + ((size_t)(n * SEQ + l0 + row)) * EMB + h * 64 + seg;
        union { __bf16 b[16]; uint4 u[2]; } tmp;
        #pragma unroll
        for (int jj = 0; jj < 4; ++jj) {
            float4 f = ((const float4*)src)[jj];
            tmp.b[jj*4+0] = (__bf16)f.x; tmp.b[jj*4+1] = (__bf16)f.y;
            tmp.b[jj*4+2] = (__bf16)f.z; tmp.b[jj*4+3] = (__bf16)f.w;
        }
        *(uint4*)&Xb[row * 72 + seg]     = tmp.u[0];
        *(uint4*)&Xb[row * 72 + seg + 8] = tmp.u[1];
    }
    __syncthreads();
    const int w = t >> 6, lane = t & 63, quad = lane >> 4, lr = lane & 15;
    bf16x8 af[2];
    #pragma unroll
    for (int ks = 0; ks < 2; ++ks)
        af[ks] = *(const bf16x8*)&Xb[(w * 16 + lr) * 72 + ks * 32 + quad * 8];
    const f32x4 zero4 = {0.f, 0.f, 0.f, 0.f};
    f32x4 acc[4];
    #pragma unroll
    for (int et = 0; et < 4; ++et) {
        acc[et] = zero4;
        #pragma unroll
        for (int ks = 0; ks < 2; ++ks) {
            bf16x8 bfrag = *(const bf16x8*)&Wb[(et * 16 + lr) * 72 + ks * 32 + quad * 8];
            acc[et] = __builtin_amdgcn_mfma_f32_16x16x32_bf16(af[ks], bfrag, acc[et], 0, 0, 0);
        }
    }
    if (z == 0) {
        #pragma unroll
        for (int et = 0; et < 4; ++et) acc[et] *= QSCALE;
    }
    __syncthreads();   // all waves past their Xb fragment reads (acc dependency)
    if (z < 2) {
        // tile[l][e] then coalesced row store
        #pragma unroll
        for (int et = 0; et < 4; ++et)
            #pragma unroll
            for (int rr = 0; rr < 4; ++rr)
                Xb[(w * 16 + quad * 4 + rr) * 72 + et * 16 + lr] = (__bf16)acc[et][rr];
        __syncthreads();
        const int row = t >> 2, seg = (t & 3) * 16;
        uint4 a = *(uint4*)&Xb[row * 72 + seg];
        uint4 b = *(uint4*)&Xb[row * 72 + seg + 8];
        __bf16* outp = (z == 0) ? qp : kp;
        __bf16* dst = outp + (size_t)nh * 65536 + (size_t)(l0 + row) * 64 + seg;
        *(uint4*)&dst[0] = a;
        *(uint4*)&dst[8] = b;
    } else {
        // tile[e][l] then coalesced row store into (N,H,64,SEQ)
        #pragma unroll
        for (int et = 0; et < 4; ++et)
            #pragma unroll
            for (int rr = 0; rr < 4; ++rr)
                Xb[(et * 16 + lr) * 72 + w * 16 + quad * 4 + rr] = (__bf16)acc[et][rr];
        __syncthreads();
        const int e = t >> 2, seg = (t & 3) * 16;
        uint4 a = *(uint4*)&Xb[e * 72 + seg];
        uint4 b = *(uint4*)&Xb[e * 72 + seg + 8];
        __bf16* dst = vpt + (size_t)nh * 65536 + (size_t)e * SEQ + l0 + seg;
        *(uint4*)&dst[0] = a;
        *(uint4*)&dst[8] = b;
    }
}

// ---------------- Kernel 2: MFMA flash attention, transposed-S, no-max softmax ----------------
// 128 queries per block (2 groups of 64), K/V chunks of 64. 1024 blocks, XCD-pinned per head.
__global__ __launch_bounds__(256, 4) void attn_mfma(
    const __bf16* __restrict__ qp, const __bf16* __restrict__ kp, const __bf16* __restrict__ vpt,
    const unsigned long long* __restrict__ mp, __bf16* __restrict__ attn_out)
{
    __shared__ __align__(16) __bf16 Ks[64 * 72];        // [key][d]
    __shared__ __align__(16) __bf16 Vt[64 * 72];        // [d][key]
    __shared__ __align__(16) __bf16 Ps[4][2][16 * 72];  // per-wave, per-group [q][key]
    const int t = threadIdx.x, w = t >> 6, lane = t & 63, quad = lane >> 4, lr = lane & 15;
    const int bid = blockIdx.x;
    const int nh = bid & 127, qg = bid >> 7;       // same head -> same XCD (stride-128 blocks)
    const int n = nh >> 4, h = nh & 15;
    const int q0 = qg * 128;
    const __bf16* Q  = qp  + (size_t)nh * 65536;
    const __bf16* K  = kp  + (size_t)nh * 65536;
    const __bf16* VT = vpt + (size_t)nh * 65536;

    int qrow[2];
    bf16x8 qf[2][2];
    const unsigned long long* mrow[2];
    #pragma unroll
    for (int g = 0; g < 2; ++g) {
        qrow[g] = q0 + g * 64 + w * 16 + lr;
        qf[g][0] = *(const bf16x8*)&Q[(size_t)qrow[g] * 64 + quad * 8];
        qf[g][1] = *(const bf16x8*)&Q[(size_t)qrow[g] * 64 + 32 + quad * 8];
        mrow[g] = mp + ((size_t)n * SEQ + qrow[g]) * 16;
    }

    const f32x4 zero4 = {0.f, 0.f, 0.f, 0.f};
    f32x4 O[2][4];
    #pragma unroll
    for (int g = 0; g < 2; ++g)
        #pragma unroll
        for (int mt = 0; mt < 4; ++mt) O[g][mt] = zero4;
    float l_part[2] = {0.f, 0.f};

    for (int kc = 0; kc < 16; ++kc) {
        __syncthreads();   // all waves done with previous Ks/Vt
        for (int c = t; c < 512; c += 256) {
            int row = c >> 3, c8 = c & 7;
            *(uint4*)&Ks[row * 72 + c8 * 8] =
                *(const uint4*)&K[(size_t)(kc * 64 + row) * 64 + c8 * 8];
            *(uint4*)&Vt[row * 72 + c8 * 8] =
                *(const uint4*)&VT[(size_t)row * SEQ + kc * 64 + c8 * 8];
        }
        const unsigned long long mw0 = mrow[0][kc], mw1 = mrow[1][kc];
        __syncthreads();
        #pragma unroll
        for (int g = 0; g < 2; ++g) {
            // S^T = K @ Q^T : col = q (lr), row = key = kt*16 + quad*4 + r
            f32x4 S[4];
            #pragma unroll
            for (int kt = 0; kt < 4; ++kt) {
                S[kt] = zero4;
                #pragma unroll
                for (int ks = 0; ks < 2; ++ks) {
                    bf16x8 kf = *(const bf16x8*)&Ks[(kt * 16 + lr) * 72 + ks * 32 + quad * 8];
                    S[kt] = __builtin_amdgcn_mfma_f32_16x16x32_bf16(kf, qf[g][ks], S[kt], 0, 0, 0);
                }
            }
            const unsigned long long mword = g ? mw1 : mw0;
            const unsigned int mlo = (unsigned int)(mword >> (quad * 4));
            const unsigned int mhi = (unsigned int)(mword >> (32 + quad * 4));
            float lsum = 0.f;
            __bf16 pb[16];
            #pragma unroll
            for (int kt = 0; kt < 4; ++kt)
                #pragma unroll
                for (int r = 0; r < 4; ++r) {
                    unsigned int bits = (kt < 2) ? mlo : mhi;
                    int sh = (kt & 1) * 16 + r;
                    float sv = ((bits >> sh) & 1u) ? S[kt][r] : MASKV;
                    float ev = EXPD(sv);            // masked -> exp underflows to exactly 0
                    lsum += ev;
                    pb[kt * 4 + r] = (__bf16)ev;
                }
            l_part[g] += lsum;
            #pragma unroll
            for (int kt = 0; kt < 4; ++kt) {
                union { __bf16 b[4]; uint2 u; } pk;
                #pragma unroll
                for (int r = 0; r < 4; ++r) pk.b[r] = pb[kt * 4 + r];
                *(uint2*)&Ps[w][g][lr * 72 + kt * 16 + quad * 4] = pk.u;
            }
        }
        __asm__ __volatile__("s_waitcnt lgkmcnt(0)" ::: "memory");  // wave-local P visibility
        // O^T += V^T @ P^T ; V-frags shared across the two q-groups
        #pragma unroll
        for (int ks = 0; ks < 2; ++ks) {
            bf16x8 pf0 = *(const bf16x8*)&Ps[w][0][lr * 72 + ks * 32 + quad * 8];
            bf16x8 pf1 = *(const bf16x8*)&Ps[w][1][lr * 72 + ks * 32 + quad * 8];
            #pragma unroll
            for (int mt = 0; mt < 4; ++mt) {
                bf16x8 vf = *(const bf16x8*)&Vt[(mt * 16 + lr) * 72 + ks * 32 + quad * 8];
                O[0][mt] = __builtin_amdgcn_mfma_f32_16x16x32_bf16(vf, pf0, O[0][mt], 0, 0, 0);
                O[1][mt] = __builtin_amdgcn_mfma_f32_16x16x32_bf16(vf, pf1, O[1][mt], 0, 0, 0);
            }
        }
    }
    #pragma unroll
    for (int g = 0; g < 2; ++g) {
        float l = l_part[g];
        l += __shfl_xor(l, 16, 64);
        l += __shfl_xor(l, 32, 64);
        const float linv = 1.0f / l;
        #pragma unroll
        for (int mt = 0; mt < 4; ++mt) {
            union { __bf16 b[4]; uint2 u; } pk;
            #pragma unroll
            for (int r = 0; r < 4; ++r) pk.b[r] = (__bf16)(O[g][mt][r] * linv);
            *(uint2*)&attn_out[((size_t)n * SEQ + qrow[g]) * EMB + h * 64 + mt * 16 + quad * 4] = pk.u;
        }
    }
}

// ---------------- Kernel 3a: Wo f32 -> bf16 ----------------
__global__ __launch_bounds__(256) void cvt_wo(const float* __restrict__ Wo, __bf16* __restrict__ Wob)
{
    int i = blockIdx.x * 256 + threadIdx.x;
    float4 f = *(const float4*)&Wo[(size_t)i * 4];
    union { __bf16 b[4]; uint2 u; } tmp;
    tmp.b[0] = (__bf16)f.x; tmp.b[1] = (__bf16)f.y; tmp.b[2] = (__bf16)f.z; tmp.b[3] = (__bf16)f.w;
    *(uint2*)&Wob[(size_t)i * 4] = tmp.u;
}

// ---------------- Kernel 3b: out = A(8192x1024) @ Wob^T + bo, MFMA, 64x128 tile ----------------
__global__ __launch_bounds__(256, 4) void out_gemm_mfma(
    const __bf16* __restrict__ A, const __bf16* __restrict__ B,
    const float* __restrict__ bo, float* __restrict__ out)
{
    __shared__ __align__(16) __bf16 As[64 * 40];
    __shared__ __align__(16) __bf16 Bs[128 * 40];
    const int t = threadIdx.x, w = t >> 6, lane = t & 63, quad = lane >> 4, lr = lane & 15;
    const int wr = (w >> 1) * 32, wc = (w & 1) * 64;
    const int r0 = blockIdx.y * 64, e0 = blockIdx.x * 128;
    const f32x4 zero4 = {0.f, 0.f, 0.f, 0.f};
    f32x4 acc[2][4];
    #pragma unroll
    for (int mt = 0; mt < 2; ++mt)
        #pragma unroll
        for (int nt = 0; nt < 4; ++nt) acc[mt][nt] = zero4;
    for (int k0 = 0; k0 < 1024; k0 += 32) {
        __syncthreads();
        {
            int row = t >> 2, c8 = t & 3;
            *(uint4*)&As[row * 40 + c8 * 8] =
                *(const uint4*)&A[(size_t)(r0 + row) * EMB + k0 + c8 * 8];
        }
        for (int c = t; c < 512; c += 256) {
            int row = c >> 2, c8 = c & 3;
            *(uint4*)&Bs[row * 40 + c8 * 8] =
                *(const uint4*)&B[(size_t)(e0 + row) * EMB + k0 + c8 * 8];
        }
        __syncthreads();
        bf16x8 af[2], bf[4];
        #pragma unroll
        for (int mt = 0; mt < 2; ++mt)
            af[mt] = *(const bf16x8*)&As[(wr + mt * 16 + lr) * 40 + quad * 8];
        #pragma unroll
        for (int nt = 0; nt < 4; ++nt)
            bf[nt] = *(const bf16x8*)&Bs[(wc + nt * 16 + lr) * 40 + quad * 8];
        #pragma unroll
        for (int mt = 0; mt < 2; ++mt)
            #pragma unroll
            for (int nt = 0; nt < 4; ++nt)
                acc[mt][nt] = __builtin_amdgcn_mfma_f32_16x16x32_bf16(af[mt], bf[nt], acc[mt][nt], 0, 0, 0);
    }
    float bv[4];
    #pragma unroll
    for (int nt = 0; nt < 4; ++nt) bv[nt] = bo[e0 + wc + nt * 16 + lr];
    #pragma unroll
    for (int mt = 0; mt < 2; ++mt)
        #pragma unroll
        for (int nt = 0; nt < 4; ++nt)
            #pragma unroll
            for (int rr = 0; rr < 4; ++rr)
                out[(size_t)(r0 + wr + mt * 16 + quad * 4 + rr) * EMB + e0 + wc + nt * 16 + lr] =
                    acc[mt][nt][rr] + bv[nt];
}

extern "C" void kernel_launch(void* const* d_in, const int* in_sizes, int n_in,
                              void* d_out, int out_size, void* d_ws, size_t ws_size,
                              hipStream_t stream) {
    const float* values = (const float*)d_in[0];
    const float* keys   = (const float*)d_in[1];
    const float* query  = (const float*)d_in[2];
    const int*   mask   = (const int*)d_in[3];
    const float* Wv     = (const float*)d_in[4];
    const float* Wk     = (const float*)d_in[5];
    const float* Wq     = (const float*)d_in[6];
    const float* Wo     = (const float*)d_in[7];
    const float* bo     = (const float*)d_in[8];
    float* out = (float*)d_out;

    const size_t per = (size_t)NB * HEADS * SEQ * HD;  // 8,388,608 elems
    __bf16* qp   = (__bf16*)d_ws;
    __bf16* kp   = qp + per;
    __bf16* vpt  = kp + per;                         // V transposed (N,H,64,SEQ)
    __bf16* attn = vpt + per;                        // (N*SEQ, EMB)
    __bf16* Wob  = attn + (size_t)NB * SEQ * EMB;
    unsigned long long* maskp = (unsigned long long*)(Wob + (size_t)EMB * EMB);

    mask_pack<<<dim3(SEQ, NB), 256, 0, stream>>>(mask, maskp);
    proj_mfma<<<dim3(16, 128, 3), 256, 0, stream>>>(query, keys, values, Wq, Wk, Wv, qp, kp, vpt);
    cvt_wo<<<1024, 256, 0, stream>>>(Wo, Wob);
    attn_mfma<<<1024, 256, 0, stream>>>(qp, kp, vpt, maskp, attn);
    out_gemm_mfma<<<dim3(EMB / 128, NB * SEQ / 64), 256, 0, stream>>>(attn, Wob, bo, out);
}